// Round 5
// baseline (731.791 us; speedup 1.0000x reference)
//
#include <hip/hip_runtime.h>
#include <cstdint>
#include <cstddef>

namespace {

constexpr int kB  = 16;
constexpr int kC  = 512;
constexpr int kCQ = 64;    // C/8
constexpr int kCV = 256;   // C/2
constexpr int kN  = 4096;  // 64*64 spatial
constexpr int kM  = 1024;  // 32*32 pooled spatial

typedef _Float16 f16;
typedef _Float16 f16x8 __attribute__((ext_vector_type(8)));
typedef float    f32x4 __attribute__((ext_vector_type(4)));

// ---------------------------------------------------------------------------
// Kernel 0: weight conversion.
//   wcat = (f16) [wq; wk; wv]   [384][512]
//   woh  = (f16)(gamma * wo)    [512][256]
// ---------------------------------------------------------------------------
__global__ __launch_bounds__(256)
void convert_weights_kernel(const float* __restrict__ wq,
                            const float* __restrict__ wk,
                            const float* __restrict__ wv,
                            const float* __restrict__ wo,
                            const float* __restrict__ gamma,
                            f16* __restrict__ wcat,
                            f16* __restrict__ woh)
{
    const int idx = blockIdx.x * 256 + threadIdx.x;
    if (idx < 49152) {
        const int e = idx * 4;
        const int r = e >> 9, c = e & 511;
        const float* src = (r < 64)  ? (wq + ((size_t)r << 9))
                         : (r < 128) ? (wk + ((size_t)(r - 64) << 9))
                                     : (wv + ((size_t)(r - 128) << 9));
        float4 v = *(const float4*)(src + c);
        union { f16 h4[4]; uint2 u; } pk;
        pk.h4[0] = (f16)v.x; pk.h4[1] = (f16)v.y;
        pk.h4[2] = (f16)v.z; pk.h4[3] = (f16)v.w;
        *(uint2*)(wcat + e) = pk.u;
    } else {
        const int e = (idx - 49152) * 4;
        const float g = gamma[0];
        float4 v = *(const float4*)(wo + e);
        union { f16 h4[4]; uint2 u; } pk;
        pk.h4[0] = (f16)(g * v.x); pk.h4[1] = (f16)(g * v.y);
        pk.h4[2] = (f16)(g * v.z); pk.h4[3] = (f16)(g * v.w);
        *(uint2*)(woh + e) = pk.u;
    }
}

// ---------------------------------------------------------------------------
// Kernel 1: MFMA projection + fused 2x2 maxpool.
//   Tile 192ch x 128n, 512 thr (8 waves = 4 ch-strips x 2 col-splits),
//   grid (nt=32, mt=0..1, b=16) = 1024 blocks; (512,4) -> 2 blocks/CU.
//   A-frags DIRECT from L2 (wcat 384KB resident, no LDS, no staging ALU).
//   B: reg-staged fp32->f16, double-buffered LDS, ONE barrier per k-step;
//   loads issued before compute, waited at the write after compute.
// ---------------------------------------------------------------------------
__global__ __launch_bounds__(512, 4)
void proj_pool_mfma(const float* __restrict__ x,
                    const f16* __restrict__ wcat,
                    f16* __restrict__ fT,   // [B][4096][64]
                    f16* __restrict__ gT,   // [B][1024][64]
                    f16* __restrict__ h)    // [B][256][1024]
{
    const int nt  = blockIdx.x;
    const int mt  = blockIdx.y;   // 0/1: 192-ch tile
    const int b   = blockIdx.z;
    const int tid = threadIdx.x;
    const int w    = tid >> 6;
    const int lane = tid & 63;
    const int quad = lane >> 4;
    const int lq   = lane & 15;
    const int wr   = w >> 1;      // 0..3: 48-ch strip
    const int wc   = w & 1;       // col split-half

    __shared__ alignas(16) f16 Bs[2][128 * 36];   // [n][k] f16, padded; 18KB

    const f16*   Ab = wcat + (size_t)mt * 192 * kC;
    const float* Xb = x + (size_t)b * kC * kN + nt * 128;

    f32x4 acc[3][4];
#pragma unroll
    for (int i = 0; i < 3; ++i)
#pragma unroll
        for (int j = 0; j < 4; ++j) acc[i][j] = {0.f, 0.f, 0.f, 0.f};

    const int bn = tid & 127;     // B: n index
    const int kg = tid >> 7;      // B: k-group of 8
    float xv[8];

    auto loadB = [&](int k0) {
#pragma unroll
        for (int j = 0; j < 8; ++j) xv[j] = Xb[(size_t)(k0 + kg * 8 + j) * kN + bn];
    };
    auto writeB = [&](int buf) {
        union { f16 hh[8]; uint4 u; } pk;
#pragma unroll
        for (int j = 0; j < 8; ++j) pk.hh[j] = (f16)xv[j];
        *(uint4*)&Bs[buf][bn * 36 + kg * 8] = pk.u;
    };

    loadB(0);
    writeB(0);
    __syncthreads();

    for (int ks = 0; ks < 16; ++ks) {
        const int cur = ks & 1;
        if (ks < 15) loadB((ks + 1) * 32);   // in flight across compute

        f16x8 bsv[4];
#pragma unroll
        for (int tj = 0; tj < 4; ++tj) {
            const int col = (tj < 2) ? (wc * 32 + tj * 16 + lq)
                                     : (64 + wc * 32 + (tj - 2) * 16 + lq);
            bsv[tj] = *(const f16x8*)&Bs[cur][col * 36 + quad * 8];
        }
        __builtin_amdgcn_s_setprio(1);
#pragma unroll
        for (int ti = 0; ti < 3; ++ti) {
            const int row = wr * 48 + ti * 16 + lq;
            const f16x8 af = *(const f16x8*)(Ab + (size_t)row * kC + ks * 32 + quad * 8);
#pragma unroll
            for (int tj = 0; tj < 4; ++tj)
                acc[ti][tj] = __builtin_amdgcn_mfma_f32_16x16x32_f16(
                    af, bsv[tj], acc[ti][tj], 0, 0, 0);
        }
        __builtin_amdgcn_s_setprio(0);

        if (ks < 15) writeB(cur ^ 1);   // vmcnt waits land here, after compute
        __syncthreads();
    }

    // ---- epilogues. D: row(ch)=quad*4+r, col(n)=lq per tile ----
#pragma unroll
    for (int ti = 0; ti < 3; ++ti) {
        const int ch0 = mt * 192 + wr * 48 + ti * 16;   // wave-uniform
        if (ch0 < 64) {
            f16* fb = fT + (size_t)b * kN * kCQ;
#pragma unroll
            for (int tj = 0; tj < 4; ++tj) {
                const int col = (tj < 2) ? (wc * 32 + tj * 16 + lq)
                                         : (64 + wc * 32 + (tj - 2) * 16 + lq);
                const int n = nt * 128 + col;
                union { f16 h4[4]; uint2 u; } pk;
#pragma unroll
                for (int r = 0; r < 4; ++r) pk.h4[r] = (f16)acc[ti][tj][r];
                *(uint2*)(fb + (size_t)n * kCQ + ch0 + quad * 4) = pk.u;
            }
        } else {
#pragma unroll
            for (int tjp = 0; tjp < 2; ++tjp) {
                float p[4];
#pragma unroll
                for (int r = 0; r < 4; ++r) {
                    float v = fmaxf(acc[ti][tjp][r], acc[ti][tjp + 2][r]);
                    v = fmaxf(v, __shfl_xor(v, 1, 64));
                    p[r] = v;
                }
                const int m = nt * 32 + wc * 16 + tjp * 8 + (lq >> 1);
                if ((lq & 1) == 0) {
                    if (ch0 < 128) {
                        union { f16 h4[4]; uint2 u; } pk;
#pragma unroll
                        for (int r = 0; r < 4; ++r) pk.h4[r] = (f16)p[r];
                        *(uint2*)(gT + ((size_t)b * kM + m) * kCQ + (ch0 - 64) + quad * 4) = pk.u;
                    } else {
#pragma unroll
                        for (int r = 0; r < 4; ++r) {
                            const int ch = ch0 - 128 + quad * 4 + r;
                            h[((size_t)b * kCV + ch) * kM + m] = (f16)p[r];
                        }
                    }
                }
            }
        }
    }
}

// ---------------------------------------------------------------------------
// Kernel 2: MFMA flash attention + fused wo GEMM + residual.
//   q-tile 64, grid (64,16)=1024 blocks.  Reg-staged g/h prefetch (loads in
//   flight across barriers), 2 barriers/chunk.  f A-frags and woh A-frags
//   direct from global (L2/L3): no fsT, no wos -> LDS 33.3KB, (256,3) ->
//   3 blocks/CU = 12 waves/CU.  GEMM2 barrier-free.
// ---------------------------------------------------------------------------
__global__ __launch_bounds__(256, 3)
void attn_out_kernel(const f16* __restrict__ fT,
                     const f16* __restrict__ gT,
                     const f16* __restrict__ hmat,
                     const f16* __restrict__ woh,   // gamma*wo, f16 [512][256]
                     const float* __restrict__ x,
                     float* __restrict__ out)
{
    const int qt   = blockIdx.x;   // 0..63: q-base qt*64
    const int b    = blockIdx.y;
    const int tid  = threadIdx.x;
    const int w    = tid >> 6;
    const int lane = tid & 63;
    const int quad = lane >> 4;
    const int lq   = lane & 15;

    __shared__ union alignas(16) SMem {
        struct {
            f16 gsT[32 * 64];    // [m][ch], XOR-swizzled 16B units (4KB)
            f16 hs[256 * 40];    // [c][m-chunk], pad 40 (20KB)
            f16 ps[64 * 36];     // [q][m], padded, wave-local (4.5KB)
        } p1;                    // 28.5KB
        struct {
            f16 osT[64 * 260];   // [q][c], wave-private rows (32.5KB)
        } p2;
    } sm;

    // ---- loop-invariant f A-frags, direct from global ----
    const int q = qt * 64 + w * 16 + lq;
    const f16* fq = fT + ((size_t)b * kN + q) * kCQ;
    const f16x8 af0 = *(const f16x8*)(fq + quad * 8);
    const f16x8 af1 = *(const f16x8*)(fq + 32 + quad * 8);

    float m_run = -3.0e38f, l_run = 0.f;
    f32x4 o_acc[16];
#pragma unroll
    for (int ci = 0; ci < 16; ++ci) o_acc[ci] = {0.f, 0.f, 0.f, 0.f};

    const f16* gTb = gT + (size_t)b * kM * kCQ;
    const f16* hb  = hmat + (size_t)b * kCV * kM;

    // ---- reg-staged prefetch ----
    const int gm = tid >> 3, gsu = tid & 7, ggu = gsu ^ (gm & 7);
    const int hc = tid >> 2, hu = tid & 3;
    uint4 pg, ph[4];
    pg = *(const uint4*)(gTb + (size_t)gm * kCQ + ggu * 8);
#pragma unroll
    for (int p = 0; p < 4; ++p)
        ph[p] = *(const uint4*)(hb + (size_t)(hc + p * 64) * kM + hu * 8);

    for (int mi = 0; mi < 32; ++mi) {
        __syncthreads();   // prior chunk's LDS reads done
        *(uint4*)&sm.p1.gsT[gm * 64 + gsu * 8] = pg;
#pragma unroll
        for (int p = 0; p < 4; ++p)
            *(uint4*)&sm.p1.hs[(hc + p * 64) * 40 + hu * 8] = ph[p];
        __syncthreads();
        if (mi < 31) {   // issue next chunk's loads; waited at next-iter writes
            const int m1 = (mi + 1) * 32;
            pg = *(const uint4*)(gTb + (size_t)(m1 + gm) * kCQ + ggu * 8);
#pragma unroll
            for (int p = 0; p < 4; ++p)
                ph[p] = *(const uint4*)(hb + (size_t)(hc + p * 64) * kM + m1 + hu * 8);
        }

        // ---- S^T = g @ f : D[m=quad*4+r (+16)][q=lq] ----
        const int mr0 = lq, mr1 = 16 + lq;
        const f16x8 bg00 = *(const f16x8*)&sm.p1.gsT[mr0 * 64 + ((quad       ^ (mr0 & 7)) * 8)];
        const f16x8 bg01 = *(const f16x8*)&sm.p1.gsT[mr0 * 64 + (((4 + quad) ^ (mr0 & 7)) * 8)];
        const f16x8 bg10 = *(const f16x8*)&sm.p1.gsT[mr1 * 64 + ((quad       ^ (mr1 & 7)) * 8)];
        const f16x8 bg11 = *(const f16x8*)&sm.p1.gsT[mr1 * 64 + (((4 + quad) ^ (mr1 & 7)) * 8)];
        f32x4 s0 = {0.f, 0.f, 0.f, 0.f}, s1 = {0.f, 0.f, 0.f, 0.f};
        s0 = __builtin_amdgcn_mfma_f32_16x16x32_f16(bg00, af0, s0, 0, 0, 0);
        s0 = __builtin_amdgcn_mfma_f32_16x16x32_f16(bg01, af1, s0, 0, 0, 0);
        s1 = __builtin_amdgcn_mfma_f32_16x16x32_f16(bg10, af0, s1, 0, 0, 0);
        s1 = __builtin_amdgcn_mfma_f32_16x16x32_f16(bg11, af1, s1, 0, 0, 0);

        // ---- per-lane online softmax (quads hold disjoint m; 2 shuffles) ----
        float cm = fmaxf(fmaxf(fmaxf(s0[0], s0[1]), fmaxf(s0[2], s0[3])),
                         fmaxf(fmaxf(s1[0], s1[1]), fmaxf(s1[2], s1[3])));
        cm = fmaxf(cm, __shfl_xor(cm, 16, 64));
        cm = fmaxf(cm, __shfl_xor(cm, 32, 64));
        const float nm = fmaxf(m_run, cm);
        const float al = __expf(m_run - nm);   // mi==0: exp(-huge)=0
        float e0[4], e1[4];
#pragma unroll
        for (int r = 0; r < 4; ++r) { e0[r] = __expf(s0[r] - nm); e1[r] = __expf(s1[r] - nm); }
        float psum = (e0[0] + e0[1]) + (e0[2] + e0[3]) + (e1[0] + e1[1]) + (e1[2] + e1[3]);
        psum += __shfl_xor(psum, 16, 64);
        psum += __shfl_xor(psum, 32, 64);
        m_run = nm;
        l_run = l_run * al + psum;

        // ---- P -> ps (wave-local), then bp frag ----
        union { f16 h4[4]; uint2 u; } pk0, pk1;
#pragma unroll
        for (int r = 0; r < 4; ++r) { pk0.h4[r] = (f16)e0[r]; pk1.h4[r] = (f16)e1[r]; }
        *(uint2*)&sm.p1.ps[(w * 16 + lq) * 36 + quad * 4]      = pk0.u;
        *(uint2*)&sm.p1.ps[(w * 16 + lq) * 36 + 16 + quad * 4] = pk1.u;
        __builtin_amdgcn_sched_barrier(0);   // bp read strictly after ps writes
        const f16x8 bp = *(const f16x8*)&sm.p1.ps[(w * 16 + lq) * 36 + quad * 8];

        // ---- PV: o[c][q] = al*o + h @ P ----
        __builtin_amdgcn_s_setprio(1);
#pragma unroll
        for (int ci = 0; ci < 16; ++ci) {
            const f16x8 ha = *(const f16x8*)&sm.p1.hs[(ci * 16 + lq) * 40 + quad * 8];
            o_acc[ci] *= al;
            o_acc[ci] = __builtin_amdgcn_mfma_f32_16x16x32_f16(ha, bp, o_acc[ci], 0, 0, 0);
        }
        __builtin_amdgcn_s_setprio(0);
    }

    const float inv = 1.0f / l_run;
    __syncthreads();   // all waves done with p1 before p2 clobber

    // ---- dump o -> osT (wave-private rows, packed 8B) ----
#pragma unroll
    for (int ci = 0; ci < 16; ++ci) {
        union { f16 h4[4]; uint2 u; } pk;
#pragma unroll
        for (int r = 0; r < 4; ++r) pk.h4[r] = (f16)(o_acc[ci][r] * inv);
        *(uint2*)&sm.p2.osT[(w * 16 + lq) * 260 + ci * 16 + quad * 4] = pk.u;
    }

    // ---- GEMM2: out = woh @ o + x ; woh A-frags direct from L2, no barriers ----
    for (int half = 0; half < 2; ++half) {
        f32x4 acc2[16];
#pragma unroll
        for (int os = 0; os < 16; ++os) acc2[os] = {0.f, 0.f, 0.f, 0.f};

        for (int ck = 0; ck < 8; ++ck) {
            const f16x8 bo = *(const f16x8*)&sm.p2.osT[(w * 16 + lq) * 260 + ck * 32 + quad * 8];
            __builtin_amdgcn_s_setprio(1);
#pragma unroll
            for (int os = 0; os < 16; ++os) {
                const f16x8 wa = *(const f16x8*)(woh +
                    (size_t)(half * 256 + os * 16 + lq) * 256 + ck * 32 + quad * 8);
                acc2[os] = __builtin_amdgcn_mfma_f32_16x16x32_f16(wa, bo, acc2[os], 0, 0, 0);
            }
            __builtin_amdgcn_s_setprio(0);
        }

        const int n0 = qt * 64 + w * 16 + lq;
#pragma unroll
        for (int os = 0; os < 16; ++os) {
#pragma unroll
            for (int r = 0; r < 4; ++r) {
                const int oc = half * 256 + os * 16 + quad * 4 + r;
                const size_t idx = ((size_t)b * kC + oc) * (size_t)kN + n0;
                out[idx] = acc2[os][r] + x[idx];
            }
        }
    }
}

}  // namespace

extern "C" void kernel_launch(void* const* d_in, const int* in_sizes, int n_in,
                              void* d_out, int out_size, void* d_ws, size_t ws_size,
                              hipStream_t stream) {
    const float* x     = (const float*)d_in[0];
    const float* wq    = (const float*)d_in[1];
    const float* wk    = (const float*)d_in[2];
    const float* wv    = (const float*)d_in[3];
    const float* wo    = (const float*)d_in[4];
    const float* gamma = (const float*)d_in[5];
    float* out = (float*)d_out;

    f16* fT   = (f16*)d_ws;
    f16* gT   = fT  + (size_t)kB * kN * kCQ;
    f16* hw   = gT  + (size_t)kB * kM * kCQ;
    f16* woh  = hw  + (size_t)kB * kCV * kM;
    f16* wcat = woh + (size_t)kC * kCV;

    hipLaunchKernelGGL(convert_weights_kernel, dim3(320), dim3(256), 0, stream,
                       wq, wk, wv, wo, gamma, wcat, woh);
    hipLaunchKernelGGL(proj_pool_mfma, dim3(32, 2, kB), dim3(512), 0, stream,
                       x, wcat, fT, gT, hw);
    hipLaunchKernelGGL(attn_out_kernel, dim3(64, kB), dim3(256), 0, stream,
                       fT, gT, hw, woh, x, out);
}

// Round 6
// 437.404 us; speedup vs baseline: 1.6730x; 1.6730x over previous
//
#include <hip/hip_runtime.h>
#include <cstdint>
#include <cstddef>

namespace {

constexpr int kB  = 16;
constexpr int kC  = 512;
constexpr int kCQ = 64;    // C/8
constexpr int kCV = 256;   // C/2
constexpr int kN  = 4096;  // 64*64 spatial
constexpr int kM  = 1024;  // 32*32 pooled spatial

typedef _Float16 f16;
typedef _Float16 f16x8 __attribute__((ext_vector_type(8)));
typedef float    f32x4 __attribute__((ext_vector_type(4)));

// ---------------------------------------------------------------------------
// Kernel 0: weight conversion.
//   wcat = (f16) [wq; wk; wv]   [384][512]
//   woh  = (f16)(gamma * wo)    [512][256]
// ---------------------------------------------------------------------------
__global__ __launch_bounds__(256)
void convert_weights_kernel(const float* __restrict__ wq,
                            const float* __restrict__ wk,
                            const float* __restrict__ wv,
                            const float* __restrict__ wo,
                            const float* __restrict__ gamma,
                            f16* __restrict__ wcat,
                            f16* __restrict__ woh)
{
    const int idx = blockIdx.x * 256 + threadIdx.x;
    if (idx < 49152) {
        const int e = idx * 4;
        const int r = e >> 9, c = e & 511;
        const float* src = (r < 64)  ? (wq + ((size_t)r << 9))
                         : (r < 128) ? (wk + ((size_t)(r - 64) << 9))
                                     : (wv + ((size_t)(r - 128) << 9));
        float4 v = *(const float4*)(src + c);
        union { f16 h4[4]; uint2 u; } pk;
        pk.h4[0] = (f16)v.x; pk.h4[1] = (f16)v.y;
        pk.h4[2] = (f16)v.z; pk.h4[3] = (f16)v.w;
        *(uint2*)(wcat + e) = pk.u;
    } else {
        const int e = (idx - 49152) * 4;
        const float g = gamma[0];
        float4 v = *(const float4*)(wo + e);
        union { f16 h4[4]; uint2 u; } pk;
        pk.h4[0] = (f16)(g * v.x); pk.h4[1] = (f16)(g * v.y);
        pk.h4[2] = (f16)(g * v.z); pk.h4[3] = (f16)(g * v.w);
        *(uint2*)(woh + e) = pk.u;
    }
}

// ---------------------------------------------------------------------------
// Kernel 1: MFMA projection + fused 2x2 maxpool.
//   Tile 192ch x 128n, 512 thr, grid (nt=32, mt=0..1, b=16).
//   A-frags from L2 with REGISTER PREFETCH (next k-step loaded during
//   current MFMAs).  B reg-staged fp32->f16 dbuf LDS, one barrier/k-step.
// ---------------------------------------------------------------------------
__global__ __launch_bounds__(512, 4)
void proj_pool_mfma(const float* __restrict__ x,
                    const f16* __restrict__ wcat,
                    f16* __restrict__ fT,   // [B][4096][64]
                    f16* __restrict__ gT,   // [B][1024][64]
                    f16* __restrict__ h)    // [B][256][1024]
{
    const int nt  = blockIdx.x;
    const int mt  = blockIdx.y;   // 0/1: 192-ch tile
    const int b   = blockIdx.z;
    const int tid = threadIdx.x;
    const int w    = tid >> 6;
    const int lane = tid & 63;
    const int quad = lane >> 4;
    const int lq   = lane & 15;
    const int wr   = w >> 1;      // 0..3: 48-ch strip
    const int wc   = w & 1;       // col split-half

    __shared__ alignas(16) f16 Bs[2][128 * 36];   // [n][k] f16, padded; 18KB

    const f16*   Ab = wcat + (size_t)mt * 192 * kC;
    const float* Xb = x + (size_t)b * kC * kN + nt * 128;

    f32x4 acc[3][4];
#pragma unroll
    for (int i = 0; i < 3; ++i)
#pragma unroll
        for (int j = 0; j < 4; ++j) acc[i][j] = {0.f, 0.f, 0.f, 0.f};

    const int bn = tid & 127;     // B: n index
    const int kg = tid >> 7;      // B: k-group of 8
    float xv[8];

    auto loadB = [&](int k0) {
#pragma unroll
        for (int j = 0; j < 8; ++j) xv[j] = Xb[(size_t)(k0 + kg * 8 + j) * kN + bn];
    };
    auto writeB = [&](int buf) {
        union { f16 hh[8]; uint4 u; } pk;
#pragma unroll
        for (int j = 0; j < 8; ++j) pk.hh[j] = (f16)xv[j];
        *(uint4*)&Bs[buf][bn * 36 + kg * 8] = pk.u;
    };

    // A-frag row base addresses (lane-fixed)
    const f16* arow[3];
#pragma unroll
    for (int ti = 0; ti < 3; ++ti)
        arow[ti] = Ab + (size_t)(wr * 48 + ti * 16 + lq) * kC + quad * 8;

    // prefetch regs
    f16x8 afp[3];
#pragma unroll
    for (int ti = 0; ti < 3; ++ti) afp[ti] = *(const f16x8*)(arow[ti]);

    loadB(0);
    writeB(0);
    __syncthreads();

    for (int ks = 0; ks < 16; ++ks) {
        const int cur = ks & 1;
        if (ks < 15) loadB((ks + 1) * 32);   // x loads in flight across compute

        f16x8 afc[3];
#pragma unroll
        for (int ti = 0; ti < 3; ++ti) afc[ti] = afp[ti];
        if (ks < 15) {
#pragma unroll
            for (int ti = 0; ti < 3; ++ti)
                afp[ti] = *(const f16x8*)(arow[ti] + (ks + 1) * 32);
        }

        f16x8 bsv[4];
#pragma unroll
        for (int tj = 0; tj < 4; ++tj) {
            const int col = (tj < 2) ? (wc * 32 + tj * 16 + lq)
                                     : (64 + wc * 32 + (tj - 2) * 16 + lq);
            bsv[tj] = *(const f16x8*)&Bs[cur][col * 36 + quad * 8];
        }
        __builtin_amdgcn_s_setprio(1);
#pragma unroll
        for (int ti = 0; ti < 3; ++ti)
#pragma unroll
            for (int tj = 0; tj < 4; ++tj)
                acc[ti][tj] = __builtin_amdgcn_mfma_f32_16x16x32_f16(
                    afc[ti], bsv[tj], acc[ti][tj], 0, 0, 0);
        __builtin_amdgcn_s_setprio(0);

        if (ks < 15) writeB(cur ^ 1);   // vmcnt waits land here, after compute
        __syncthreads();
    }

    // ---- epilogues. D: row(ch)=quad*4+r, col(n)=lq per tile ----
#pragma unroll
    for (int ti = 0; ti < 3; ++ti) {
        const int ch0 = mt * 192 + wr * 48 + ti * 16;   // wave-uniform
        if (ch0 < 64) {
            f16* fb = fT + (size_t)b * kN * kCQ;
#pragma unroll
            for (int tj = 0; tj < 4; ++tj) {
                const int col = (tj < 2) ? (wc * 32 + tj * 16 + lq)
                                         : (64 + wc * 32 + (tj - 2) * 16 + lq);
                const int n = nt * 128 + col;
                union { f16 h4[4]; uint2 u; } pk;
#pragma unroll
                for (int r = 0; r < 4; ++r) pk.h4[r] = (f16)acc[ti][tj][r];
                *(uint2*)(fb + (size_t)n * kCQ + ch0 + quad * 4) = pk.u;
            }
        } else {
#pragma unroll
            for (int tjp = 0; tjp < 2; ++tjp) {
                float p[4];
#pragma unroll
                for (int r = 0; r < 4; ++r) {
                    float v = fmaxf(acc[ti][tjp][r], acc[ti][tjp + 2][r]);
                    v = fmaxf(v, __shfl_xor(v, 1, 64));
                    p[r] = v;
                }
                const int m = nt * 32 + wc * 16 + tjp * 8 + (lq >> 1);
                if ((lq & 1) == 0) {
                    if (ch0 < 128) {
                        union { f16 h4[4]; uint2 u; } pk;
#pragma unroll
                        for (int r = 0; r < 4; ++r) pk.h4[r] = (f16)p[r];
                        *(uint2*)(gT + ((size_t)b * kM + m) * kCQ + (ch0 - 64) + quad * 4) = pk.u;
                    } else {
#pragma unroll
                        for (int r = 0; r < 4; ++r) {
                            const int ch = ch0 - 128 + quad * 4 + r;
                            h[((size_t)b * kCV + ch) * kM + m] = (f16)p[r];
                        }
                    }
                }
            }
        }
    }
}

// ---------------------------------------------------------------------------
// Kernel 2: MFMA flash attention + fused wo GEMM + residual.
//   R3 structure (2 q-tiles/block, fsT + wos in LDS) with DOUBLE-BUFFERED
//   staging and ONE barrier per chunk / per GEMM2 slab.
//   Grid (32,16)=512 blocks; LDS 73KB -> 2 blocks/CU.
// ---------------------------------------------------------------------------
__global__ __launch_bounds__(256, 2)
void attn_out_kernel(const f16* __restrict__ fT,
                     const f16* __restrict__ gT,
                     const f16* __restrict__ hmat,
                     const f16* __restrict__ woh,   // gamma*wo, f16 [512][256]
                     const float* __restrict__ x,
                     float* __restrict__ out)
{
    const int qt   = blockIdx.x;   // 0..31: q-base qt*128
    const int b    = blockIdx.y;
    const int tid  = threadIdx.x;
    const int w    = tid >> 6;
    const int lane = tid & 63;
    const int quad = lane >> 4;
    const int lq   = lane & 15;

    __shared__ union alignas(16) SMem {
        struct {
            f16 fsT[128 * 72];     // [q][ch], both tiles (18KB)
            f16 gsT[2][32 * 64];   // [m][ch], XOR-swizzled, dbuf (8KB)
            f16 hs[2][256 * 40];   // [c][m-chunk], pad 40, dbuf (40KB)
            f16 ps[64 * 40];       // [q-local][m], wave-local (5KB)
        } p1;                      // 72704 B
        struct {
            f16 osT[64 * 264];     // [q-local][c] (33.8KB)
            f16 wos[2][256 * 40];  // [oc'][k-slab], dbuf (41KB)
        } p2;                      // 74752 B
    } sm;

    // ---- stage fsT [128 q][64 ch] (16 KB) ----
    {
        const f16* fb = fT + ((size_t)b * kN + qt * 128) * kCQ;
#pragma unroll
        for (int p = 0; p < 4; ++p) {
            const int unit = tid + p * 256;
            const int q = unit >> 3, u = unit & 7;
            *(uint4*)&sm.p1.fsT[q * 72 + u * 8] = *(const uint4*)(fb + q * 64 + u * 8);
        }
    }
    __syncthreads();

    // loop-invariant f frags for both tiles (q-local = w*16+lq)
    const f16x8 afA0 = *(const f16x8*)&sm.p1.fsT[(w * 16 + lq) * 72 + quad * 8];
    const f16x8 afA1 = *(const f16x8*)&sm.p1.fsT[(w * 16 + lq) * 72 + 32 + quad * 8];
    const f16x8 afB0 = *(const f16x8*)&sm.p1.fsT[(64 + w * 16 + lq) * 72 + quad * 8];
    const f16x8 afB1 = *(const f16x8*)&sm.p1.fsT[(64 + w * 16 + lq) * 72 + 32 + quad * 8];

    float mA = -3.0e38f, lA = 0.f, mB = -3.0e38f, lB = 0.f;
    f32x4 o_accA[16], o_accB[16];
#pragma unroll
    for (int ci = 0; ci < 16; ++ci) {
        o_accA[ci] = {0.f, 0.f, 0.f, 0.f};
        o_accB[ci] = {0.f, 0.f, 0.f, 0.f};
    }

    const f16* gTb = gT + (size_t)b * kM * kCQ;
    const f16* hb  = hmat + (size_t)b * kCV * kM;

    // ---- reg-staged prefetch for g/h chunks ----
    const int gm = tid >> 3, gsu = tid & 7, ggu = gsu ^ (gm & 7);
    const int hc = tid >> 2, hu = tid & 3;
    uint4 pg, ph[4];
    auto load_chunk = [&](int m0) {
        pg = *(const uint4*)(gTb + (size_t)(m0 + gm) * kCQ + ggu * 8);
#pragma unroll
        for (int p = 0; p < 4; ++p)
            ph[p] = *(const uint4*)(hb + (size_t)(hc + p * 64) * kM + m0 + hu * 8);
    };
    auto write_chunk = [&](int buf) {
        *(uint4*)&sm.p1.gsT[buf][gm * 64 + gsu * 8] = pg;
#pragma unroll
        for (int p = 0; p < 4; ++p)
            *(uint4*)&sm.p1.hs[buf][(hc + p * 64) * 40 + hu * 8] = ph[p];
    };

    load_chunk(0);
    write_chunk(0);
    load_chunk(32);            // chunk 1 in flight
    __syncthreads();

    for (int mi = 0; mi < 32; ++mi) {
        const int cur = mi & 1;
        if (mi < 31) write_chunk(cur ^ 1);     // chunk mi+1 (vmcnt hidden)
        if (mi < 30) load_chunk((mi + 2) * 32);

        // ---- S^T = g @ f for both tiles: D[m=quad*4+r (+16)][q=lq] ----
        const int mr0 = lq, mr1 = 16 + lq;
        const f16* gsc = &sm.p1.gsT[cur][0];
        const f16x8 bg00 = *(const f16x8*)&gsc[mr0 * 64 + ((quad       ^ (mr0 & 7)) * 8)];
        const f16x8 bg01 = *(const f16x8*)&gsc[mr0 * 64 + (((4 + quad) ^ (mr0 & 7)) * 8)];
        const f16x8 bg10 = *(const f16x8*)&gsc[mr1 * 64 + ((quad       ^ (mr1 & 7)) * 8)];
        const f16x8 bg11 = *(const f16x8*)&gsc[mr1 * 64 + (((4 + quad) ^ (mr1 & 7)) * 8)];
        f32x4 s0A = {0.f,0.f,0.f,0.f}, s1A = {0.f,0.f,0.f,0.f};
        f32x4 s0B = {0.f,0.f,0.f,0.f}, s1B = {0.f,0.f,0.f,0.f};
        s0A = __builtin_amdgcn_mfma_f32_16x16x32_f16(bg00, afA0, s0A, 0, 0, 0);
        s0A = __builtin_amdgcn_mfma_f32_16x16x32_f16(bg01, afA1, s0A, 0, 0, 0);
        s1A = __builtin_amdgcn_mfma_f32_16x16x32_f16(bg10, afA0, s1A, 0, 0, 0);
        s1A = __builtin_amdgcn_mfma_f32_16x16x32_f16(bg11, afA1, s1A, 0, 0, 0);
        s0B = __builtin_amdgcn_mfma_f32_16x16x32_f16(bg00, afB0, s0B, 0, 0, 0);
        s0B = __builtin_amdgcn_mfma_f32_16x16x32_f16(bg01, afB1, s0B, 0, 0, 0);
        s1B = __builtin_amdgcn_mfma_f32_16x16x32_f16(bg10, afB0, s1B, 0, 0, 0);
        s1B = __builtin_amdgcn_mfma_f32_16x16x32_f16(bg11, afB1, s1B, 0, 0, 0);

        // ---- per-lane online softmax, tile A (q = w*16+lq) ----
        float alA;
        {
            float cm = fmaxf(fmaxf(fmaxf(s0A[0], s0A[1]), fmaxf(s0A[2], s0A[3])),
                             fmaxf(fmaxf(s1A[0], s1A[1]), fmaxf(s1A[2], s1A[3])));
            cm = fmaxf(cm, __shfl_xor(cm, 16, 64));
            cm = fmaxf(cm, __shfl_xor(cm, 32, 64));
            const float nm = fmaxf(mA, cm);
            alA = __expf(mA - nm);
            float e0[4], e1[4];
#pragma unroll
            for (int r = 0; r < 4; ++r) { e0[r] = __expf(s0A[r] - nm); e1[r] = __expf(s1A[r] - nm); }
            float psum = (e0[0]+e0[1])+(e0[2]+e0[3])+(e1[0]+e1[1])+(e1[2]+e1[3]);
            psum += __shfl_xor(psum, 16, 64);
            psum += __shfl_xor(psum, 32, 64);
            mA = nm;
            lA = lA * alA + psum;
            union { f16 h4[4]; uint2 u; } pk0, pk1;
#pragma unroll
            for (int r = 0; r < 4; ++r) { pk0.h4[r] = (f16)e0[r]; pk1.h4[r] = (f16)e1[r]; }
            *(uint2*)&sm.p1.ps[(w * 16 + lq) * 40 + quad * 4]      = pk0.u;
            *(uint2*)&sm.p1.ps[(w * 16 + lq) * 40 + 16 + quad * 4] = pk1.u;
        }
        const f16x8 bpA = *(const f16x8*)&sm.p1.ps[(w * 16 + lq) * 40 + quad * 8];
        __builtin_amdgcn_sched_barrier(0);   // bpA read before ps overwrite

        // ---- per-lane online softmax, tile B (q = 64 + w*16+lq) ----
        float alB;
        {
            float cm = fmaxf(fmaxf(fmaxf(s0B[0], s0B[1]), fmaxf(s0B[2], s0B[3])),
                             fmaxf(fmaxf(s1B[0], s1B[1]), fmaxf(s1B[2], s1B[3])));
            cm = fmaxf(cm, __shfl_xor(cm, 16, 64));
            cm = fmaxf(cm, __shfl_xor(cm, 32, 64));
            const float nm = fmaxf(mB, cm);
            alB = __expf(mB - nm);
            float e0[4], e1[4];
#pragma unroll
            for (int r = 0; r < 4; ++r) { e0[r] = __expf(s0B[r] - nm); e1[r] = __expf(s1B[r] - nm); }
            float psum = (e0[0]+e0[1])+(e0[2]+e0[3])+(e1[0]+e1[1])+(e1[2]+e1[3]);
            psum += __shfl_xor(psum, 16, 64);
            psum += __shfl_xor(psum, 32, 64);
            mB = nm;
            lB = lB * alB + psum;
            union { f16 h4[4]; uint2 u; } pk0, pk1;
#pragma unroll
            for (int r = 0; r < 4; ++r) { pk0.h4[r] = (f16)e0[r]; pk1.h4[r] = (f16)e1[r]; }
            *(uint2*)&sm.p1.ps[(w * 16 + lq) * 40 + quad * 4]      = pk0.u;
            *(uint2*)&sm.p1.ps[(w * 16 + lq) * 40 + 16 + quad * 4] = pk1.u;
        }
        const f16x8 bpB = *(const f16x8*)&sm.p1.ps[(w * 16 + lq) * 40 + quad * 8];
        __builtin_amdgcn_sched_barrier(0);

        // ---- PV for both tiles: shared ha reads ----
        __builtin_amdgcn_s_setprio(1);
#pragma unroll
        for (int ci = 0; ci < 16; ++ci) {
            const f16x8 ha = *(const f16x8*)&sm.p1.hs[cur][(ci * 16 + lq) * 40 + quad * 8];
            o_accA[ci] *= alA;
            o_accA[ci] = __builtin_amdgcn_mfma_f32_16x16x32_f16(ha, bpA, o_accA[ci], 0, 0, 0);
            o_accB[ci] *= alB;
            o_accB[ci] = __builtin_amdgcn_mfma_f32_16x16x32_f16(ha, bpB, o_accB[ci], 0, 0, 0);
        }
        __builtin_amdgcn_s_setprio(0);

        __syncthreads();   // single barrier per chunk
    }

    const float invA = 1.0f / lA;
    const float invB = 1.0f / lB;

    // ---- dump tile A -> osT (p1 reads all done at final loop barrier) ----
#pragma unroll
    for (int ci = 0; ci < 16; ++ci) {
        union { f16 h4[4]; uint2 u; } pk;
#pragma unroll
        for (int r = 0; r < 4; ++r) pk.h4[r] = (f16)(o_accA[ci][r] * invA);
        *(uint2*)&sm.p2.osT[(w * 16 + lq) * 264 + ci * 16 + quad * 4] = pk.u;
    }

    // ---- GEMM2 staging helpers (wos dbuf, one barrier per slab) ----
    const int woc = tid >> 2, wu = tid & 3;
    uint4 pw[4];
    auto load_w = [&](int sp) {   // sp = half*8 + ck, 0..15
#pragma unroll
        for (int p = 0; p < 4; ++p)
            pw[p] = *(const uint4*)(woh +
                (size_t)((sp >> 3) * 256 + woc + p * 64) * 256 + (sp & 7) * 32 + wu * 8);
    };
    auto write_w = [&](int buf) {
#pragma unroll
        for (int p = 0; p < 4; ++p)
            *(uint4*)&sm.p2.wos[buf][(woc + p * 64) * 40 + wu * 8] = pw[p];
    };

    load_w(0);
    write_w(0);
    load_w(1);
    __syncthreads();   // wos[0] + osT(A) visible

    // ---- GEMM2 x2 tiles: out = woh @ o + x ----
    for (int tile = 0; tile < 2; ++tile) {
        for (int half = 0; half < 2; ++half) {
            f32x4 acc2[16];
#pragma unroll
            for (int os = 0; os < 16; ++os) acc2[os] = {0.f, 0.f, 0.f, 0.f};

            for (int ck = 0; ck < 8; ++ck) {
                const int sidx = tile * 16 + half * 8 + ck;   // 0..31
                const int cur2 = sidx & 1;
                if (sidx < 31) write_w(cur2 ^ 1);             // next slab
                if (sidx < 30) load_w((sidx + 2) & 15);

                const f16x8 bo = *(const f16x8*)&sm.p2.osT[(w * 16 + lq) * 264 + ck * 32 + quad * 8];
                __builtin_amdgcn_s_setprio(1);
#pragma unroll
                for (int os = 0; os < 16; ++os) {
                    const f16x8 wa = *(const f16x8*)&sm.p2.wos[cur2][(os * 16 + lq) * 40 + quad * 8];
                    acc2[os] = __builtin_amdgcn_mfma_f32_16x16x32_f16(wa, bo, acc2[os], 0, 0, 0);
                }
                __builtin_amdgcn_s_setprio(0);
                __syncthreads();   // reads of wos[cur2] done before its rewrite
            }

            const int n0 = qt * 128 + tile * 64 + w * 16 + lq;
#pragma unroll
            for (int os = 0; os < 16; ++os) {
#pragma unroll
                for (int r = 0; r < 4; ++r) {
                    const int oc = half * 256 + os * 16 + quad * 4 + r;
                    const size_t idx = ((size_t)b * kC + oc) * (size_t)kN + n0;
                    out[idx] = acc2[os][r] + x[idx];
                }
            }
        }
        if (tile == 0) {
            // dump tile B -> osT (rows wave-private; own reads done)
#pragma unroll
            for (int ci = 0; ci < 16; ++ci) {
                union { f16 h4[4]; uint2 u; } pk;
#pragma unroll
                for (int r = 0; r < 4; ++r) pk.h4[r] = (f16)(o_accB[ci][r] * invB);
                *(uint2*)&sm.p2.osT[(w * 16 + lq) * 264 + ci * 16 + quad * 4] = pk.u;
            }
        }
    }
}

}  // namespace

extern "C" void kernel_launch(void* const* d_in, const int* in_sizes, int n_in,
                              void* d_out, int out_size, void* d_ws, size_t ws_size,
                              hipStream_t stream) {
    const float* x     = (const float*)d_in[0];
    const float* wq    = (const float*)d_in[1];
    const float* wk    = (const float*)d_in[2];
    const float* wv    = (const float*)d_in[3];
    const float* wo    = (const float*)d_in[4];
    const float* gamma = (const float*)d_in[5];
    float* out = (float*)d_out;

    f16* fT   = (f16*)d_ws;
    f16* gT   = fT  + (size_t)kB * kN * kCQ;
    f16* hw   = gT  + (size_t)kB * kM * kCQ;
    f16* woh  = hw  + (size_t)kB * kCV * kM;
    f16* wcat = woh + (size_t)kC * kCV;

    hipLaunchKernelGGL(convert_weights_kernel, dim3(320), dim3(256), 0, stream,
                       wq, wk, wv, wo, gamma, wcat, woh);
    hipLaunchKernelGGL(proj_pool_mfma, dim3(32, 2, kB), dim3(512), 0, stream,
                       x, wcat, fT, gT, hw);
    hipLaunchKernelGGL(attn_out_kernel, dim3(32, kB), dim3(256), 0, stream,
                       fT, gT, hw, woh, x, out);
}